// Round 13
// baseline (258.596 us; speedup 1.0000x reference)
//
#include <hip/hip_runtime.h>

// ---------------------------------------------------------------------------
// NNSensorResponse: out[s,t] = sum_{b,n} sigmoid(MLPp(x))*MLPa(x)*mask * gauss(t-z)
// B=4,N=8000 (BN=32000), F_IN=3, HID=128, S=1024, T=1024, sigma runtime (=5.0).
// Gaussian band-limited (sigma=5 -> +-31 ticks): 16 buckets of 64-tick
// granularity, each owning a 128-tick span.
// R13: 2-node DAG.
//   N1 k_pre: hidden states (unsorted, fragment-gatherable rows) + W2 frag
//             shuffle + d_out zero. No histogram.
//   N2 k_main: each block REBUILDS its bucket's electron list itself from z
//             (L2-resident 128KB; 2-pass deterministic ballot compaction into
//             ushort LDS list, ~5us) -> no sort kernels, no global list.
//             Per chunk: gather H rows (prefetched), Gaussian B-fragments
//             computed from per-thread REGISTER params between barriers ->
//             2 barriers/chunk. All LDS tiles use XOR-rotation layouts
//             (R12's stride-34 hit 8 of 32 banks: 6.97M conflict cycles).
//             atomicAdd epilogue (d_out zeroed in N1).
// ---------------------------------------------------------------------------

#define BN_E   32000
#define HIDW   128
#define S_DIM  1024
#define T_DIM  1024
#define NBKT   16
#define KSPL   4
#define LCAP   3584         // LDS list capacity (max bucket ~3130 for uniform z)
#define INV_SQRT_2PI 0.3989422804f

// k_pre block ranges
#define HB 16000            // hidden blocks (2 e/block)
#define WB 128              // W2 shuffle blocks
#define ZB 1024             // d_out zero blocks

typedef __attribute__((ext_vector_type(8))) unsigned short u16x8;
typedef __attribute__((ext_vector_type(8))) __bf16         bf16x8;
typedef __attribute__((ext_vector_type(4))) float          f32x4;

static __device__ __forceinline__ unsigned short f2bf(float f) {
    union { float f; unsigned int u; } v; v.f = f;
    unsigned int r = v.u + 0x7FFFu + ((v.u >> 16) & 1u);   // RNE, inputs finite
    return (unsigned short)(r >> 16);
}

static __device__ __forceinline__ f32x4 mfma16(u16x8 a, u16x8 b, f32x4 c) {
    return __builtin_amdgcn_mfma_f32_16x16x32_bf16(
        __builtin_bit_cast(bf16x8, a), __builtin_bit_cast(bf16x8, b), c, 0, 0, 0);
}

static __device__ __forceinline__ int bucket_of(float z) {
    int b = (int)floorf((z - 31.f) * (1.f / 64.f));
    return min(max(b, 0), NBKT - 1);
}

// ---------------- N1: hidden (unsorted) + W2 shuffle + zero -----------------
__global__ __launch_bounds__(256) void k_pre(
    const float* __restrict__ x,
    const float* __restrict__ Wp1, const float* __restrict__ bp1,
    const float* __restrict__ Wa1, const float* __restrict__ ba1,
    const float* __restrict__ Wp2, const float* __restrict__ Wa2,
    unsigned short* __restrict__ HpU, unsigned short* __restrict__ HaU,
    unsigned short* __restrict__ WfP, unsigned short* __restrict__ WfA,
    float* __restrict__ out) {
    int bx = blockIdx.x, tid = threadIdx.x;
    if (bx < HB) {
        // hidden layers, natural row layout HpU[e*128 + j]
        int e = bx * 2 + (tid >> 7);
        int j = tid & 127;
        float x0 = x[e * 3 + 0], x1 = x[e * 3 + 1], x2 = x[e * 3 + 2];
        float hp = x0 * Wp1[j] + x1 * Wp1[HIDW + j] + x2 * Wp1[2 * HIDW + j] + bp1[j];
        float ha = x0 * Wa1[j] + x1 * Wa1[HIDW + j] + x2 * Wa1[2 * HIDW + j] + ba1[j];
        HpU[e * HIDW + j] = f2bf(fmaxf(hp, 0.f));
        HaU[e * HIDW + j] = f2bf(fmaxf(ha, 0.f));
    } else if (bx < HB + WB) {
        // W2 -> MFMA fragment order (coalesced in s)
        int bid = bx - HB;                        // 0..127
        const float* src = (bid & 64) ? Wa2 : Wp2;
        unsigned short* dst = (bid & 64) ? WfA : WfP;
        int rem = bid & 63;
        int kq = rem >> 2;                        // ks*4+q
        int s  = (rem & 3) * 256 + tid;
        int ks = kq >> 2, q = kq & 3;
        unsigned short fr[8];
#pragma unroll
        for (int j = 0; j < 8; ++j)
            fr[j] = f2bf(src[(ks * 32 + q * 8 + j) * S_DIM + s]);
        ((u16x8*)dst)[kq * S_DIM + s] = *(u16x8*)fr;
    } else {
        // zero d_out (atomic epilogue; harness poisons 0xAA)
        int idx = (bx - HB - WB) * 256 + tid;
        ((f32x4*)out)[idx] = (f32x4){0.f, 0.f, 0.f, 0.f};
    }
}

// ---------------- N2: main --------------------------------------------------
// grid: (NBKT*KSPL = 64, 16 s_tiles of 64), 256 threads (4 waves).
__global__ __launch_bounds__(256, 4) void k_main(
    const unsigned short* __restrict__ HpU, const unsigned short* __restrict__ HaU,
    const unsigned short* __restrict__ WfP, const unsigned short* __restrict__ WfA,
    const float* __restrict__ bp2, const float* __restrict__ ba2,
    const float* __restrict__ zp, const float* __restrict__ maskg,
    const float* __restrict__ sigp, float* __restrict__ out) {

    const int bk   = blockIdx.x >> 2;          // KSPL = 4
    const int kspl = blockIdx.x & 3;
    const int s0   = blockIdx.y * 64;
    const int tb   = bk * 64;                  // t span [tb, tb+128)

    const int tid = threadIdx.x;
    const int w = tid >> 6, l = tid & 63, q = l >> 4, c = l & 15;

    // LDS: bucket list (ushort) + rotated Hp/Ha/GL + Rsp
    __shared__ unsigned short listL[LCAP];                 //  7168 B
    __shared__ __align__(16) uint4 HpL[512];               //  8192 B
    __shared__ __align__(16) uint4 HaL[512];               //  8192 B
    __shared__ __align__(16) uint4 GL[512];                //  8192 B
    __shared__ __align__(16) unsigned short RspL[64 * 40]; //  5120 B
    __shared__ int wcnt[4];

    // ---- self-sort: 2-pass deterministic ballot compaction (bucket bk) ----
    int myCnt = 0;
    for (int it = w; it < BN_E / 64; it += 4) {            // 125 iters/wave
        int e = it * 64 + l;
        unsigned long long m = __ballot(bucket_of(zp[e]) == bk);
        myCnt += (int)__popcll(m);
    }
    if (l == 0) wcnt[w] = myCnt;
    __syncthreads();
    int base = 0;
#pragma unroll
    for (int i = 0; i < 4; ++i) if (i < w) base += wcnt[i];
    const int cntB = min(wcnt[0] + wcnt[1] + wcnt[2] + wcnt[3], LCAP);
    for (int it = w; it < BN_E / 64; it += 4) {
        int e = it * 64 + l;
        bool hit = bucket_of(zp[e]) == bk;
        unsigned long long m = __ballot(hit);
        int rank = (int)__popcll(m & ((l == 0) ? 0ull : ((1ull << l) - 1ull)));
        int p = base + rank;
        if (hit && p < LCAP) listL[p] = (unsigned short)e;
        base += (int)__popcll(m);
    }
    __syncthreads();

    const int nch = (cntB + 31) >> 5;
    const int per = (nch + KSPL - 1) >> 2;
    const int c0  = kspl * per;
    const int c1  = min(nch, c0 + per);
    if (c0 >= c1) return;                      // uniform; no barriers below skip

    // W2 fragments for this wave's 16 s-columns: 8 coalesced 16B loads.
    const u16x8* WfPv = (const u16x8*)WfP;
    const u16x8* WfAv = (const u16x8*)WfA;
    const int sg = s0 + w * 16 + c;
    u16x8 wP[4], wA[4];
#pragma unroll
    for (int ks = 0; ks < 4; ++ks) {
        wP[ks] = WfPv[(ks * 4 + q) * S_DIM + sg];
        wA[ks] = WfAv[(ks * 4 + q) * S_DIM + sg];
    }
    const float bp2v = bp2[sg];
    const float ba2v = ba2[sg];

    const float sigma = sigp[0];
    const float coef  = INV_SQRT_2PI / sigma;
    const float nis2  = -1.f / (2.f * sigma * sigma);

    const f32x4 z4 = { 0.f, 0.f, 0.f, 0.f };
    f32x4 acc2[8];
#pragma unroll
    for (int n8 = 0; n8 < 8; ++n8) acc2[n8] = z4;

    const uint4* Hp4 = (const uint4*)HpU;      // row e = 16 uint4 (fragment units)
    const uint4* Ha4 = (const uint4*)HaU;
    const u16x8* HpV = (const u16x8*)HpL;
    const u16x8* HaV = (const u16x8*)HaL;
    const u16x8* GLv = (const u16x8*)GL;

    // roles: H staging (e_l row, units kq0 & kq0+8); Gaussian group q4 (8 e)
    const int e_l = tid >> 3, kq0 = tid & 7;
    const int q4 = (tid >> 4) & 3;

    // ---- prologue prefetch for chunk c0 ----
    int pos = c0 * 32 + e_l;
    int evH = (pos < cntB) ? (int)listL[pos] : 0;
    uint4 p0 = Hp4[evH * 16 + kq0], p1 = Hp4[evH * 16 + kq0 + 8];
    uint4 a0 = Ha4[evH * 16 + kq0], a1 = Ha4[evH * 16 + kq0 + 8];

    for (int ci = c0; ci < c1; ++ci) {
        // Gaussian params for this thread's 8 electrons (L1-hot broadcasts)
        float zr[8], cr[8];
#pragma unroll
        for (int j = 0; j < 8; ++j) {
            int pe = ci * 32 + q4 * 8 + j;
            bool rj = pe < cntB;
            int evj = rj ? (int)listL[pe] : 0;
            zr[j] = rj ? zp[evj] : 0.f;
            cr[j] = rj ? coef * maskg[evj] : 0.f;
        }

        __syncthreads();                       // A: prior chunk's LDS reads done
        HpL[kq0 * 32 + ((e_l + kq0) & 31)]           = p0;
        HpL[(kq0 + 8) * 32 + ((e_l + kq0 + 8) & 31)] = p1;
        HaL[kq0 * 32 + ((e_l + kq0) & 31)]           = a0;
        HaL[(kq0 + 8) * 32 + ((e_l + kq0 + 8) & 31)] = a1;

        // Gaussian tile from registers -> GL (rotated layout)
#pragma unroll
        for (int uu = 0; uu < 2; ++uu) {
            int u = tid + uu * 256;            // 0..511
            int g = u >> 4, cc = u & 15;       // g = n8*4+q4
            float tt = (float)(tb + (g >> 2) * 16 + cc);
            unsigned short g8[8];
#pragma unroll
            for (int j = 0; j < 8; ++j) {
                float d = tt - zr[j];
                g8[j] = f2bf(cr[j] * __expf(d * d * nis2));
            }
            GL[g * 16 + ((cc + g) & 15)] = *(uint4*)g8;
        }
        __syncthreads();                       // B: stage + GL visible

        // prefetch next chunk's H rows (overlaps GEMM compute)
        int nc = min(ci + 1, c1 - 1);
        int posn = nc * 32 + e_l;
        int evn = (posn < cntB) ? (int)listL[posn] : 0;
        p0 = Hp4[evn * 16 + kq0]; p1 = Hp4[evn * 16 + kq0 + 8];
        a0 = Ha4[evn * 16 + kq0]; a1 = Ha4[evn * 16 + kq0 + 8];

        // GEMM1: C1[e][s] = H[e][k] @ W2[k][s]  (M=e 32, N=s 16/wave, K=128)
        f32x4 aP[2], aA[2];
#pragma unroll
        for (int m = 0; m < 2; ++m) { aP[m] = z4; aA[m] = z4; }
#pragma unroll
        for (int ks = 0; ks < 4; ++ks) {
            int kq = ks * 4 + q;
            u16x8 hp0 = HpV[kq * 32 + ((c + kq) & 31)];
            u16x8 hp1 = HpV[kq * 32 + ((c + 16 + kq) & 31)];
            u16x8 ha0 = HaV[kq * 32 + ((c + kq) & 31)];
            u16x8 ha1 = HaV[kq * 32 + ((c + 16 + kq) & 31)];
            aP[0] = mfma16(hp0, wP[ks], aP[0]);
            aP[1] = mfma16(hp1, wP[ks], aP[1]);
            aA[0] = mfma16(ha0, wA[ks], aA[0]);
            aA[1] = mfma16(ha1, wA[ks], aA[1]);
        }

        // epilogue1: rsp = sigmoid(p+bp2)*(a+ba2); C-layout -> RspL[s][e]
        // rows wave-private; DS in-order per wave -> no barrier needed
#pragma unroll
        for (int m = 0; m < 2; ++m) {
            f32x4 p = aP[m], a = aA[m];
            unsigned long long pk = 0;
#pragma unroll
            for (int r = 0; r < 4; ++r) {
                float pr = p[r] + bp2v;
                float ar = a[r] + ba2v;
                float sg2 = __builtin_amdgcn_rcpf(1.f + __expf(-pr));
                pk |= (unsigned long long)f2bf(sg2 * ar) << (16 * r);
            }
            int sl = w * 16 + c;                 // col of C1 = s
            int e0 = m * 16 + q * 4;             // row of C1 = e
            *(unsigned long long*)&RspL[sl * 40 + e0] = pk;
        }

        // GEMM2: out[s][t] += Rsp[s][e] @ G[e][t]  (M=s 16/wave, N=t 128, K=32)
        u16x8 afr = *(const u16x8*)&RspL[(w * 16 + c) * 40 + q * 8];
#pragma unroll
        for (int n8 = 0; n8 < 8; ++n8) {
            int g = n8 * 4 + q;
            acc2[n8] = mfma16(afr, GLv[g * 16 + ((c + g) & 15)], acc2[n8]);
        }
    }

    // epilogue2: atomic accumulate (bucket spans overlap + ksplit)
#pragma unroll
    for (int n8 = 0; n8 < 8; ++n8) {
        int t = tb + n8 * 16 + c;
        if (t < T_DIM) {
            int srow = s0 + w * 16 + q * 4;
#pragma unroll
            for (int r = 0; r < 4; ++r)
                atomicAdd(&out[(srow + r) * T_DIM + t], acc2[n8][r]);
        }
    }
}

// ---------------- launch ----------------

extern "C" void kernel_launch(void* const* d_in, const int* in_sizes, int n_in,
                              void* d_out, int out_size, void* d_ws, size_t ws_size,
                              hipStream_t stream) {
    const float* x    = (const float*)d_in[0];
    const float* zp   = (const float*)d_in[1];
    const float* mask = (const float*)d_in[2];
    const float* Wp1  = (const float*)d_in[3];
    const float* bp1  = (const float*)d_in[4];
    const float* Wp2  = (const float*)d_in[5];
    const float* bp2  = (const float*)d_in[6];
    const float* Wa1  = (const float*)d_in[7];
    const float* ba1  = (const float*)d_in[8];
    const float* Wa2  = (const float*)d_in[9];
    const float* ba2  = (const float*)d_in[10];
    const float* sig  = (const float*)d_in[11];

    char* ws = (char*)d_ws;
    unsigned short* HpU  = (unsigned short*)(ws);                      // 8,192,000 B
    unsigned short* HaU  = (unsigned short*)(ws + 8192000);            // 8,192,000 B
    unsigned short* WfP  = (unsigned short*)(ws + 16384000);           //   262,144 B
    unsigned short* WfA  = (unsigned short*)(ws + 16646144);           //   262,144 B
    // total ws ~16.9 MB

    k_pre<<<HB + WB + ZB, 256, 0, stream>>>(
        x, Wp1, bp1, Wa1, ba1, Wp2, Wa2, HpU, HaU, WfP, WfA, (float*)d_out);
    k_main<<<dim3(NBKT * KSPL, 16, 1), 256, 0, stream>>>(
        HpU, HaU, WfP, WfA, bp2, ba2, zp, mask, sig, (float*)d_out);
}